// Round 5
// baseline (852.133 us; speedup 1.0000x reference)
//
#include <hip/hip_runtime.h>
#include <cstdint>
#include <cstddef>

#define N_USER 100000
#define N_ITEM 50000
#define CDIM   128
#define NEDGE  600000
#define N_SEG  (N_ITEM + N_USER)          // item segments first, then user
#define NB_SCAN ((N_SEG + 255) / 256)     // 586 scan blocks

typedef __bf16 bf16_t;
typedef bf16_t bfvec8 __attribute__((ext_vector_type(8)));
typedef float  f32x4  __attribute__((ext_vector_type(4)));

// ---------------------------------------------------------------------------
// GEMM body (R3-proven): Y[M,128] = act(X@W + bias). fp32 in/out, bf16 MFMA.
// W staged transposed in LDS, Wt[n][k], row stride LDW=136 elems.
// MFMA 16x16x32_bf16: A[m=lane&15][k=quad*8+j], B[k][n=lane&15],
// D reg r -> row=quad*4+r, col=lane&15.  In-place safe (row-disjoint blocks).
// ---------------------------------------------------------------------------
#define LDW 136

template <bool RELU>
static __device__ void gemm_ldw_body(bf16_t* Wt,
    const float* X, const float* __restrict__ W, const float* __restrict__ B,
    float* Y, int M, int bx)
{
    const int tid = threadIdx.x;
    {
        const f32x4* W4 = reinterpret_cast<const f32x4*>(W);
        #pragma unroll
        for (int i = 0; i < 16; ++i) {
            int cidx = i * 256 + tid;
            int base = cidx * 4;
            int k  = base >> 7;
            int n0 = base & 127;
            f32x4 v = W4[cidx];
            #pragma unroll
            for (int j = 0; j < 4; ++j) Wt[(n0 + j) * LDW + k] = (bf16_t)v[j];
        }
    }
    __syncthreads();

    const int wave = tid >> 6, lane = tid & 63;
    const int quad = lane >> 4, ln16 = lane & 15;

    #pragma unroll
    for (int s = 0; s < 2; ++s) {
        int row0 = bx * 128 + s * 64 + wave * 16;
        int arow = row0 + ln16;
        int arow_c = arow < M ? arow : 0;

        bfvec8 a[4];
        const float* xp = X + (size_t)arow_c * CDIM + quad * 8;
        #pragma unroll
        for (int kc = 0; kc < 4; ++kc) {
            f32x4 lo = *reinterpret_cast<const f32x4*>(xp + kc * 32);
            f32x4 hi = *reinterpret_cast<const f32x4*>(xp + kc * 32 + 4);
            #pragma unroll
            for (int j = 0; j < 4; ++j) {
                a[kc][j]     = (bf16_t)lo[j];
                a[kc][j + 4] = (bf16_t)hi[j];
            }
        }

        f32x4 acc[8];
        #pragma unroll
        for (int t = 0; t < 8; ++t) acc[t] = (f32x4){0.f, 0.f, 0.f, 0.f};

        #pragma unroll
        for (int t = 0; t < 8; ++t) {
            const bf16_t* wp = &Wt[(t * 16 + ln16) * LDW + quad * 8];
            #pragma unroll
            for (int kc = 0; kc < 4; ++kc) {
                bfvec8 b = *reinterpret_cast<const bfvec8*>(wp + kc * 32);
                acc[t] = __builtin_amdgcn_mfma_f32_16x16x32_bf16(a[kc], b, acc[t], 0, 0, 0);
            }
        }

        if (row0 < M) {
            #pragma unroll
            for (int t = 0; t < 8; ++t) {
                int col = t * 16 + ln16;
                float bias = B[col];
                #pragma unroll
                for (int r = 0; r < 4; ++r) {
                    int row = row0 + quad * 4 + r;
                    if (row < M) {
                        float v = acc[t][r] + bias;
                        if (RELU) v = v > 0.f ? v : 0.f;
                        Y[(size_t)row * CDIM + col] = v;
                    }
                }
            }
        }
    }
}

template <bool RELU>
__global__ __launch_bounds__(256) void gemm128(
    const float* X, const float* __restrict__ W, const float* __restrict__ B,
    float* Y, int M)
{
    __shared__ __align__(16) bf16_t Wt[128 * LDW];
    gemm_ldw_body<RELU>(Wt, X, W, B, Y, M, blockIdx.x);
}

// ---------------------------------------------------------------------------
// CSR build pieces (R3-proven)
// ---------------------------------------------------------------------------
__global__ __launch_bounds__(256) void zero_i32(int* __restrict__ p, int n)
{
    int i = blockIdx.x * 256 + threadIdx.x;
    if (i < n) p[i] = 0;
}

__global__ __launch_bounds__(256) void hist_k(
    const int* __restrict__ edge_ui, const int* __restrict__ edge_iu,
    int* __restrict__ deg)
{
    int i = blockIdx.x * 256 + threadIdx.x;
    if (i >= NEDGE) return;
    atomicAdd(&deg[edge_ui[NEDGE + i]], 1);
    atomicAdd(&deg[N_ITEM + edge_iu[NEDGE + i]], 1);
}

__global__ __launch_bounds__(256) void block_scan(
    int* __restrict__ off, int* __restrict__ bsum, int n)
{
    __shared__ int sh[256];
    int tid = threadIdx.x;
    int i = blockIdx.x * 256 + tid;
    int v = (i < n) ? off[i] : 0;
    sh[tid] = v;
    __syncthreads();
    #pragma unroll
    for (int d = 1; d < 256; d <<= 1) {
        int t = (tid >= d) ? sh[tid - d] : 0;
        __syncthreads();
        sh[tid] += t;
        __syncthreads();
    }
    if (i < n) off[i] = sh[tid] - v;
    if (tid == 255) bsum[blockIdx.x] = sh[255];
}

__global__ __launch_bounds__(1024) void scan_bsums(int* __restrict__ bsum)
{
    __shared__ int sh[1024];
    int tid = threadIdx.x;
    int v = (tid < NB_SCAN) ? bsum[tid] : 0;
    sh[tid] = v;
    __syncthreads();
    #pragma unroll
    for (int d = 1; d < 1024; d <<= 1) {
        int t = (tid >= d) ? sh[tid - d] : 0;
        __syncthreads();
        sh[tid] += t;
        __syncthreads();
    }
    if (tid < NB_SCAN) bsum[tid] = sh[tid] - v;
    if (tid == 1023) bsum[NB_SCAN] = sh[1023];
}

__global__ __launch_bounds__(256) void add_offsets(
    int* __restrict__ off, const int* __restrict__ bsum,
    int* __restrict__ cursor, int n)
{
    int i = blockIdx.x * 256 + threadIdx.x;
    if (i < n) {
        int o = off[i] + bsum[i >> 8];
        off[i] = o;
        cursor[i] = o;
    } else if (i == n) {
        off[n] = bsum[NB_SCAN];
    }
}

// ---------------------------------------------------------------------------
// Fused: CSR bucket-fill (latency-bound long pole) || both init projections.
// Fill branch = R3's fill_k verbatim; GEMM branch = R3's gemm128 body.
// ---------------------------------------------------------------------------
__global__ __launch_bounds__(256) void fill_and_init(
    const float* __restrict__ x_user, const float* __restrict__ x_item,
    const float* __restrict__ W_init, const float* __restrict__ b_init,
    float* __restrict__ xu, float* __restrict__ xi,
    const int* __restrict__ edge_ui, const int* __restrict__ edge_iu,
    int* __restrict__ cursor, int* __restrict__ srcbuf)
{
    __shared__ __align__(16) bf16_t Wt[128 * LDW];
    const int gFill = (NEDGE + 255) / 256;
    const int gU = (N_USER + 127) / 128;
    int b = blockIdx.x;
    if (b < gFill) {
        int i = b * 256 + threadIdx.x;
        if (i >= NEDGE) return;
        {
            int dst = edge_ui[NEDGE + i];
            int slot = atomicAdd(&cursor[dst], 1);
            srcbuf[slot] = edge_ui[i];
        }
        {
            int dst = edge_iu[NEDGE + i];
            int slot = atomicAdd(&cursor[N_ITEM + dst], 1);
            srcbuf[slot] = edge_iu[i];
        }
        return;
    }
    b -= gFill;
    if (b < gU) {
        gemm_ldw_body<false>(Wt, x_user, W_init, b_init, xu, N_USER, b);
    } else {
        gemm_ldw_body<false>(Wt, x_item, W_init + 16384, b_init + 128, xi, N_ITEM, b - gU);
    }
}

// ---------------------------------------------------------------------------
// Gather + GIN combine for BOTH node types in one launch.
// One wave per dst node. Lane holds float4 (32 lanes cover a 128-ch row);
// the two half-waves walk alternate neighbors, then combine via lane^32
// shuffle. out = (1+eps)*x[node] + sum_nbrs F[src].
// ---------------------------------------------------------------------------
__global__ __launch_bounds__(256) void gather_both(
    const float* __restrict__ xu, const float* __restrict__ xi,
    const float* __restrict__ eps2,            // eps + 2*l: [item, user]
    const int* __restrict__ off_all, const int* __restrict__ srcbuf,
    float* __restrict__ ti, float* __restrict__ tu)
{
    const int gBI = (N_ITEM + 3) / 4;
    int b = blockIdx.x;
    bool isItem = b < gBI;
    int wave = threadIdx.x >> 6;
    int node = (isItem ? b : b - gBI) * 4 + wave;
    int n = isItem ? N_ITEM : N_USER;
    if (node >= n) return;

    const f32x4* F = reinterpret_cast<const f32x4*>(isItem ? xu : xi);
    const f32x4* X = reinterpret_cast<const f32x4*>(isItem ? xi : xu);
    const int* off = isItem ? off_all : off_all + N_ITEM;
    f32x4* out = reinterpret_cast<f32x4*>(isItem ? ti : tu);
    float s = 1.f + (isItem ? eps2[0] : eps2[1]);

    int l32  = threadIdx.x & 31;
    int half = (threadIdx.x >> 5) & 1;
    int start = off[node], end = off[node + 1];

    f32x4 acc = (f32x4){0.f, 0.f, 0.f, 0.f};
    int e = start + half;
    for (; e + 2 < end; e += 4) {
        int s0 = srcbuf[e];
        int s1 = srcbuf[e + 2];
        f32x4 v0 = F[(size_t)s0 * 32 + l32];
        f32x4 v1 = F[(size_t)s1 * 32 + l32];
        acc += v0 + v1;
    }
    for (; e < end; e += 2) {
        int s0 = srcbuf[e];
        acc += F[(size_t)s0 * 32 + l32];
    }
    // combine the two half-wave partial sums
    f32x4 oth;
    #pragma unroll
    for (int j = 0; j < 4; ++j) oth[j] = __shfl_xor(acc[j], 32, 64);
    acc += oth;

    if (half == 0) {
        f32x4 xv = X[(size_t)node * 32 + l32];
        out[(size_t)node * 32 + l32] = s * xv + acc;
    }
}

// ---------------------------------------------------------------------------
// LayerNorm over 128 channels + affine + ReLU (R3-proven). One wave per row.
// ---------------------------------------------------------------------------
__global__ __launch_bounds__(256) void ln_relu(
    const float* __restrict__ H,
    const float* __restrict__ G,
    const float* __restrict__ Bb,
    float* __restrict__ out, int rows)
{
    int wave = threadIdx.x >> 6, lane = threadIdx.x & 63;
    int row = blockIdx.x * 4 + wave;
    if (row >= rows) return;
    float2 v = reinterpret_cast<const float2*>(H + (size_t)row * CDIM)[lane];
    float s = v.x + v.y;
    #pragma unroll
    for (int m = 32; m >= 1; m >>= 1) s += __shfl_xor(s, m, 64);
    float mean = s * (1.f / 128.f);
    float d0 = v.x - mean, d1 = v.y - mean;
    float q = d0 * d0 + d1 * d1;
    #pragma unroll
    for (int m = 32; m >= 1; m >>= 1) q += __shfl_xor(q, m, 64);
    float rs = rsqrtf(q * (1.f / 128.f) + 1e-5f);
    float2 g = reinterpret_cast<const float2*>(G)[lane];
    float2 b = reinterpret_cast<const float2*>(Bb)[lane];
    float y0 = d0 * rs * g.x + b.x;
    float y1 = d1 * rs * g.y + b.y;
    y0 = y0 > 0.f ? y0 : 0.f;
    y1 = y1 > 0.f ? y1 : 0.f;
    float2 o; o.x = y0; o.y = y1;
    reinterpret_cast<float2*>(out + (size_t)row * CDIM)[lane] = o;
}

// ---------------------------------------------------------------------------
extern "C" void kernel_launch(void* const* d_in, const int* in_sizes, int n_in,
                              void* d_out, int out_size, void* d_ws, size_t ws_size,
                              hipStream_t stream)
{
    const float* x_user = (const float*)d_in[0];
    const float* x_item = (const float*)d_in[1];
    const float* W_init = (const float*)d_in[2];
    const float* b_init = (const float*)d_in[3];
    const float* mlp_W  = (const float*)d_in[4];
    const float* mlp_b  = (const float*)d_in[5];
    const float* eps    = (const float*)d_in[6];
    const float* ln_g   = (const float*)d_in[7];
    const float* ln_b   = (const float*)d_in[8];
    const int* edge_ui  = (const int*)d_in[9];
    const int* edge_iu  = (const int*)d_in[10];

    float* xu = (float*)d_out;                      // [N_USER,128]
    float* xi = xu + (size_t)N_USER * CDIM;         // [N_ITEM,128]

    float* tu = (float*)d_ws;                       // 51.2 MB
    float* ti = tu + (size_t)N_USER * CDIM;         // 25.6 MB
    int* off_all = (int*)(ti + (size_t)N_ITEM * CDIM);
    int* cursor  = off_all + (N_SEG + 4);
    int* bsum    = cursor + N_SEG;
    int* srcbuf  = bsum + (NB_SCAN + 2);            // 2*NEDGE

    const int gU = (N_USER + 127) / 128;            // 782
    const int gI = (N_ITEM + 127) / 128;            // 391
    const int gSeg = (N_SEG + 256) / 256;
    const int gE = (NEDGE + 255) / 256;             // 2344
    const int gGather = (N_ITEM + 3) / 4 + (N_USER + 3) / 4;

    // CSR prep
    zero_i32<<<(N_SEG + 255) / 256, 256, 0, stream>>>(off_all, N_SEG);
    hist_k<<<gE, 256, 0, stream>>>(edge_ui, edge_iu, off_all);
    block_scan<<<NB_SCAN, 256, 0, stream>>>(off_all, bsum, N_SEG);
    scan_bsums<<<1, 1024, 0, stream>>>(bsum);
    add_offsets<<<gSeg, 256, 0, stream>>>(off_all, bsum, cursor, N_SEG);

    // fill (long pole) co-scheduled with both init projections
    fill_and_init<<<gE + gU + gI, 256, 0, stream>>>(
        x_user, x_item, W_init, b_init, xu, xi, edge_ui, edge_iu, cursor, srcbuf);

    for (int l = 0; l < 2; ++l) {
        gather_both<<<gGather, 256, 0, stream>>>(
            xu, xi, eps + 2 * l, off_all, srcbuf, ti, tu);

        // item MLP (in-place), then user MLP (in-place) — R3-proven
        gemm128<true><<<gI, 256, 0, stream>>>(ti, mlp_W + (size_t)((l * 2 + 0) * 2 + 0) * 16384,
                                              mlp_b + ((l * 2 + 0) * 2 + 0) * 128, ti, N_ITEM);
        gemm128<true><<<gI, 256, 0, stream>>>(ti, mlp_W + (size_t)((l * 2 + 0) * 2 + 1) * 16384,
                                              mlp_b + ((l * 2 + 0) * 2 + 1) * 128, ti, N_ITEM);
        gemm128<true><<<gU, 256, 0, stream>>>(tu, mlp_W + (size_t)((l * 2 + 1) * 2 + 0) * 16384,
                                              mlp_b + ((l * 2 + 1) * 2 + 0) * 128, tu, N_USER);
        gemm128<true><<<gU, 256, 0, stream>>>(tu, mlp_W + (size_t)((l * 2 + 1) * 2 + 1) * 16384,
                                              mlp_b + ((l * 2 + 1) * 2 + 1) * 128, tu, N_USER);

        // LayerNorm+ReLU: node type 0 = user, 1 = item
        ln_relu<<<(N_USER + 3) / 4, 256, 0, stream>>>(tu, ln_g + (l * 2 + 0) * 128, ln_b + (l * 2 + 0) * 128, xu, N_USER);
        ln_relu<<<(N_ITEM + 3) / 4, 256, 0, stream>>>(ti, ln_g + (l * 2 + 1) * 128, ln_b + (l * 2 + 1) * 128, xi, N_ITEM);
    }
}

// Round 7
// 707.548 us; speedup vs baseline: 1.2043x; 1.2043x over previous
//
#include <hip/hip_runtime.h>
#include <cstdint>
#include <cstddef>

#define N_USER 100000
#define N_ITEM 50000
#define CDIM   128
#define NEDGE  600000
#define N_SEG  (N_ITEM + N_USER)          // item segments first, then user
#define NB_SCAN ((N_SEG + 255) / 256)     // 586 scan blocks

typedef __bf16 bf16_t;
typedef bf16_t bfvec8 __attribute__((ext_vector_type(8)));
typedef float  f32x4  __attribute__((ext_vector_type(4)));

// LDS row stride for 128-wide bf16 tiles: 136 elems = 272 B. 16B-aligned rows,
// fragment reads land 2 lanes/bank (free, m136). Proven in R3/R5 GEMM.
#define LDW 136

// Stage a 128x128 fp32 weight (row-major [k][n]) into LDS as bf16 Wt[n][k].
static __device__ inline void stage_w(bf16_t* Wt, const float* __restrict__ W, int tid) {
    const f32x4* W4 = reinterpret_cast<const f32x4*>(W);
    #pragma unroll
    for (int i = 0; i < 16; ++i) {
        int cidx = i * 256 + tid;
        int base = cidx * 4;
        int k  = base >> 7;
        int n0 = base & 127;
        f32x4 v = W4[cidx];
        #pragma unroll
        for (int j = 0; j < 4; ++j) Wt[(n0 + j) * LDW + k] = (bf16_t)v[j];
    }
}

// ---------------------------------------------------------------------------
// GEMM body (R3/R5-proven): Y[M,128] = act(X@W + bias). fp32 in/out, bf16
// MFMA fp32-acc. MFMA 16x16x32_bf16: A[m=lane&15][k=quad*8+j],
// B[k][n=lane&15], D reg r -> row=quad*4+r, col=lane&15.
// ---------------------------------------------------------------------------
template <bool RELU>
static __device__ void gemm_ldw_body(bf16_t* Wt,
    const float* X, const float* __restrict__ W, const float* __restrict__ B,
    float* Y, int M, int bx)
{
    const int tid = threadIdx.x;
    stage_w(Wt, W, tid);
    __syncthreads();

    const int wave = tid >> 6, lane = tid & 63;
    const int quad = lane >> 4, ln16 = lane & 15;

    #pragma unroll
    for (int s = 0; s < 2; ++s) {
        int row0 = bx * 128 + s * 64 + wave * 16;
        int arow = row0 + ln16;
        int arow_c = arow < M ? arow : 0;

        bfvec8 a[4];
        const float* xp = X + (size_t)arow_c * CDIM + quad * 8;
        #pragma unroll
        for (int kc = 0; kc < 4; ++kc) {
            f32x4 lo = *reinterpret_cast<const f32x4*>(xp + kc * 32);
            f32x4 hi = *reinterpret_cast<const f32x4*>(xp + kc * 32 + 4);
            #pragma unroll
            for (int j = 0; j < 4; ++j) {
                a[kc][j]     = (bf16_t)lo[j];
                a[kc][j + 4] = (bf16_t)hi[j];
            }
        }

        f32x4 acc[8];
        #pragma unroll
        for (int t = 0; t < 8; ++t) acc[t] = (f32x4){0.f, 0.f, 0.f, 0.f};

        #pragma unroll
        for (int t = 0; t < 8; ++t) {
            const bf16_t* wp = &Wt[(t * 16 + ln16) * LDW + quad * 8];
            #pragma unroll
            for (int kc = 0; kc < 4; ++kc) {
                bfvec8 b = *reinterpret_cast<const bfvec8*>(wp + kc * 32);
                acc[t] = __builtin_amdgcn_mfma_f32_16x16x32_bf16(a[kc], b, acc[t], 0, 0, 0);
            }
        }

        if (row0 < M) {
            #pragma unroll
            for (int t = 0; t < 8; ++t) {
                int col = t * 16 + ln16;
                float bias = B[col];
                #pragma unroll
                for (int r = 0; r < 4; ++r) {
                    int row = row0 + quad * 4 + r;
                    if (row < M) {
                        float v = acc[t][r] + bias;
                        if (RELU) v = v > 0.f ? v : 0.f;
                        Y[(size_t)row * CDIM + col] = v;
                    }
                }
            }
        }
    }
}

template <bool RELU>
__global__ __launch_bounds__(256) void gemm128(
    const float* X, const float* __restrict__ W, const float* __restrict__ B,
    float* Y, int M)
{
    __shared__ __align__(16) bf16_t Wt[128 * LDW];
    gemm_ldw_body<RELU>(Wt, X, W, B, Y, M, blockIdx.x);
}

// ---------------------------------------------------------------------------
// CSR build pieces (proven)
// ---------------------------------------------------------------------------
__global__ __launch_bounds__(256) void zero_i32(int* __restrict__ p, int n)
{
    int i = blockIdx.x * 256 + threadIdx.x;
    if (i < n) p[i] = 0;
}

__global__ __launch_bounds__(256) void hist_k(
    const int* __restrict__ edge_ui, const int* __restrict__ edge_iu,
    int* __restrict__ deg)
{
    int i = blockIdx.x * 256 + threadIdx.x;
    if (i >= NEDGE) return;
    atomicAdd(&deg[edge_ui[NEDGE + i]], 1);
    atomicAdd(&deg[N_ITEM + edge_iu[NEDGE + i]], 1);
}

__global__ __launch_bounds__(256) void block_scan(
    int* __restrict__ off, int* __restrict__ bsum, int n)
{
    __shared__ int sh[256];
    int tid = threadIdx.x;
    int i = blockIdx.x * 256 + tid;
    int v = (i < n) ? off[i] : 0;
    sh[tid] = v;
    __syncthreads();
    #pragma unroll
    for (int d = 1; d < 256; d <<= 1) {
        int t = (tid >= d) ? sh[tid - d] : 0;
        __syncthreads();
        sh[tid] += t;
        __syncthreads();
    }
    if (i < n) off[i] = sh[tid] - v;
    if (tid == 255) bsum[blockIdx.x] = sh[255];
}

__global__ __launch_bounds__(1024) void scan_bsums(int* __restrict__ bsum)
{
    __shared__ int sh[1024];
    int tid = threadIdx.x;
    int v = (tid < NB_SCAN) ? bsum[tid] : 0;
    sh[tid] = v;
    __syncthreads();
    #pragma unroll
    for (int d = 1; d < 1024; d <<= 1) {
        int t = (tid >= d) ? sh[tid - d] : 0;
        __syncthreads();
        sh[tid] += t;
        __syncthreads();
    }
    if (tid < NB_SCAN) bsum[tid] = sh[tid] - v;
    if (tid == 1023) bsum[NB_SCAN] = sh[1023];
}

__global__ __launch_bounds__(256) void add_offsets(
    int* __restrict__ off, const int* __restrict__ bsum,
    int* __restrict__ cursor, int n)
{
    int i = blockIdx.x * 256 + threadIdx.x;
    if (i < n) {
        int o = off[i] + bsum[i >> 8];
        off[i] = o;
        cursor[i] = o;
    } else if (i == n) {
        off[n] = bsum[NB_SCAN];
    }
}

// standalone bucket fill — no LDS, high occupancy (R5 post-mortem: fusing
// with init charged 34.8KB LDS to fill blocks, occupancy 80%->35%, net loss)
__global__ __launch_bounds__(256) void fill_k(
    const int* __restrict__ edge_ui, const int* __restrict__ edge_iu,
    int* __restrict__ cursor, int* __restrict__ srcbuf)
{
    int i = blockIdx.x * 256 + threadIdx.x;
    if (i >= NEDGE) return;
    {
        int dst = edge_ui[NEDGE + i];
        int slot = atomicAdd(&cursor[dst], 1);
        srcbuf[slot] = edge_ui[i];
    }
    {
        int dst = edge_iu[NEDGE + i];
        int slot = atomicAdd(&cursor[N_ITEM + dst], 1);
        srcbuf[slot] = edge_iu[i];
    }
}

// ---------------------------------------------------------------------------
// Gather + GIN combine for BOTH node types (proven R5/R6).
// One wave per dst node; lane = float4 (32 lanes/row); half-waves alternate
// neighbors, combined via lane^32 shuffle. out = (1+eps)*x + sum F[src].
// ---------------------------------------------------------------------------
__global__ __launch_bounds__(256) void gather_both(
    const float* __restrict__ xu, const float* __restrict__ xi,
    const float* __restrict__ eps2,            // eps + 2*l: [item, user]
    const int* __restrict__ off_all, const int* __restrict__ srcbuf,
    float* __restrict__ ti, float* __restrict__ tu)
{
    const int gBI = (N_ITEM + 3) / 4;
    int b = blockIdx.x;
    bool isItem = b < gBI;
    int wave = threadIdx.x >> 6;
    int node = (isItem ? b : b - gBI) * 4 + wave;
    int n = isItem ? N_ITEM : N_USER;
    if (node >= n) return;

    const f32x4* F = reinterpret_cast<const f32x4*>(isItem ? xu : xi);
    const f32x4* X = reinterpret_cast<const f32x4*>(isItem ? xi : xu);
    const int* off = isItem ? off_all : off_all + N_ITEM;
    f32x4* out = reinterpret_cast<f32x4*>(isItem ? ti : tu);
    float s = 1.f + (isItem ? eps2[0] : eps2[1]);

    int l32  = threadIdx.x & 31;
    int half = (threadIdx.x >> 5) & 1;
    int start = off[node], end = off[node + 1];

    f32x4 acc = (f32x4){0.f, 0.f, 0.f, 0.f};
    int e = start + half;
    for (; e + 6 < end; e += 8) {
        int s0 = srcbuf[e];
        int s1 = srcbuf[e + 2];
        int s2 = srcbuf[e + 4];
        int s3 = srcbuf[e + 6];
        f32x4 v0 = F[(size_t)s0 * 32 + l32];
        f32x4 v1 = F[(size_t)s1 * 32 + l32];
        f32x4 v2 = F[(size_t)s2 * 32 + l32];
        f32x4 v3 = F[(size_t)s3 * 32 + l32];
        acc += (v0 + v1) + (v2 + v3);
    }
    for (; e + 2 < end; e += 4) {
        int s0 = srcbuf[e];
        int s1 = srcbuf[e + 2];
        acc += F[(size_t)s0 * 32 + l32] + F[(size_t)s1 * 32 + l32];
    }
    for (; e < end; e += 2) {
        acc += F[(size_t)srcbuf[e] * 32 + l32];
    }
    f32x4 oth;
    #pragma unroll
    for (int j = 0; j < 4; ++j) oth[j] = __shfl_xor(acc[j], 32, 64);
    acc += oth;

    if (half == 0) {
        f32x4 xv = X[(size_t)node * 32 + l32];
        out[(size_t)node * 32 + l32] = s * xv + acc;
    }
}

// ---------------------------------------------------------------------------
// Fused MLP (linear->ReLU x NN=2) + LayerNorm + ReLU, both node types,
// 128 rows/block. Wt and At both use the proven LDW=136 linear layout.
// H1 round-trips through At (bf16 — same rounding as the unfused path).
// *** R6 bug fixed here: reference applies ReLU after the SECOND linear too
// (before LayerNorm) — rectify acc after the B2 bias add, pre-LN stats. ***
// LN per output row via quad-wide shfl_xor width-16 reductions.
// LDS 69,632 B -> 2 blocks/CU.
// ---------------------------------------------------------------------------
__global__ __launch_bounds__(256) void mlp_ln_both(
    const float* __restrict__ ti, const float* __restrict__ tu,
    const float* __restrict__ mlpW,   // mlp_W + l*4*16384
    const float* __restrict__ mlpb,   // mlp_b + l*4*128
    const float* __restrict__ lng,    // ln_g + l*2*128
    const float* __restrict__ lnb,    // ln_b + l*2*128
    float* __restrict__ xi, float* __restrict__ xu)
{
    __shared__ __align__(16) bf16_t Wt[128 * LDW];
    __shared__ __align__(16) bf16_t At[128 * LDW];

    const int gBI = (N_ITEM + 127) / 128;
    int b = blockIdx.x;
    bool isItem = b < gBI;
    const float* X = isItem ? ti : tu;
    float* Y       = isItem ? xi : xu;
    int M  = isItem ? N_ITEM : N_USER;
    int bx = isItem ? b : b - gBI;
    // edge type 0 = (user->item) => item dst; 1 = (item->user) => user dst
    const float* W1 = mlpW + (isItem ? 0 : 2) * 16384;
    const float* W2 = W1 + 16384;
    const float* B1 = mlpb + (isItem ? 0 : 2) * 128;
    const float* B2 = B1 + 128;
    // node type 0 = user, 1 = item
    const float* G  = lng + (isItem ? 128 : 0);
    const float* Bb = lnb + (isItem ? 128 : 0);

    const int tid = threadIdx.x;
    stage_w(Wt, W1, tid);
    __syncthreads();

    const int wave = tid >> 6, lane = tid & 63;
    const int quad = lane >> 4, ln16 = lane & 15;
    const int rowBase = bx * 128;

    // ---- GEMM1: X -> relu(X@W1+b1) -> At[row][k] (bf16, stride LDW) ----
    #pragma unroll
    for (int s = 0; s < 2; ++s) {
        int row0l = s * 64 + wave * 16;
        int arow = rowBase + row0l + ln16;
        int arow_c = arow < M ? arow : 0;

        bfvec8 a[4];
        const float* xp = X + (size_t)arow_c * CDIM + quad * 8;
        #pragma unroll
        for (int kc = 0; kc < 4; ++kc) {
            f32x4 lo = *reinterpret_cast<const f32x4*>(xp + kc * 32);
            f32x4 hi = *reinterpret_cast<const f32x4*>(xp + kc * 32 + 4);
            #pragma unroll
            for (int j = 0; j < 4; ++j) {
                a[kc][j]     = (bf16_t)lo[j];
                a[kc][j + 4] = (bf16_t)hi[j];
            }
        }

        f32x4 acc[8];
        #pragma unroll
        for (int t = 0; t < 8; ++t) acc[t] = (f32x4){0.f, 0.f, 0.f, 0.f};
        #pragma unroll
        for (int t = 0; t < 8; ++t) {
            const bf16_t* wp = &Wt[(t * 16 + ln16) * LDW + quad * 8];
            #pragma unroll
            for (int kc = 0; kc < 4; ++kc) {
                bfvec8 bv = *reinterpret_cast<const bfvec8*>(wp + kc * 32);
                acc[t] = __builtin_amdgcn_mfma_f32_16x16x32_bf16(a[kc], bv, acc[t], 0, 0, 0);
            }
        }

        // D(row=quad*4+r, col=t*16+ln16) -> At[row][col], relu applied
        #pragma unroll
        for (int t = 0; t < 8; ++t) {
            int col = t * 16 + ln16;
            float bias = B1[col];
            #pragma unroll
            for (int r = 0; r < 4; ++r) {
                float v = acc[t][r] + bias;
                v = v > 0.f ? v : 0.f;
                At[(row0l + quad * 4 + r) * LDW + col] = (bf16_t)v;
            }
        }
    }
    __syncthreads();
    stage_w(Wt, W2, tid);      // overwrite W1; all GEMM1 reads complete
    __syncthreads();

    // ---- GEMM2 from At + bias + ReLU + LayerNorm + ReLU -> Y ----
    #pragma unroll
    for (int s = 0; s < 2; ++s) {
        int row0l = s * 64 + wave * 16;
        int ml = row0l + ln16;

        bfvec8 a[4];
        #pragma unroll
        for (int kc = 0; kc < 4; ++kc)
            a[kc] = *reinterpret_cast<const bfvec8*>(&At[ml * LDW + kc * 32 + quad * 8]);

        f32x4 acc[8];
        #pragma unroll
        for (int t = 0; t < 8; ++t) acc[t] = (f32x4){0.f, 0.f, 0.f, 0.f};
        #pragma unroll
        for (int t = 0; t < 8; ++t) {
            const bf16_t* wp = &Wt[(t * 16 + ln16) * LDW + quad * 8];
            #pragma unroll
            for (int kc = 0; kc < 4; ++kc) {
                bfvec8 bv = *reinterpret_cast<const bfvec8*>(wp + kc * 32);
                acc[t] = __builtin_amdgcn_mfma_f32_16x16x32_bf16(a[kc], bv, acc[t], 0, 0, 0);
            }
        }

        float gA[8], bA[8];
        #pragma unroll
        for (int t = 0; t < 8; ++t) {
            int col = t * 16 + ln16;
            float b2 = B2[col];
            #pragma unroll
            for (int r = 0; r < 4; ++r) {
                float v = acc[t][r] + b2;
                acc[t][r] = v > 0.f ? v : 0.f;       // <-- the missing ReLU (R4/R6 bug)
            }
            gA[t] = G[col]; bA[t] = Bb[col];
        }

        // LN: row (quad*4+r) spans 8 regs x the 16 lanes of this quad
        #pragma unroll
        for (int r = 0; r < 4; ++r) {
            float sm = 0.f;
            #pragma unroll
            for (int t = 0; t < 8; ++t) sm += acc[t][r];
            #pragma unroll
            for (int m = 8; m >= 1; m >>= 1) sm += __shfl_xor(sm, m, 16);
            float mean = sm * (1.f / 128.f);
            float sq = 0.f;
            #pragma unroll
            for (int t = 0; t < 8; ++t) { float d = acc[t][r] - mean; sq += d * d; }
            #pragma unroll
            for (int m = 8; m >= 1; m >>= 1) sq += __shfl_xor(sq, m, 16);
            float rs = rsqrtf(sq * (1.f / 128.f) + 1e-5f);

            int row = rowBase + row0l + quad * 4 + r;
            if (row < M) {
                #pragma unroll
                for (int t = 0; t < 8; ++t) {
                    float y = (acc[t][r] - mean) * rs * gA[t] + bA[t];
                    y = y > 0.f ? y : 0.f;
                    Y[(size_t)row * CDIM + t * 16 + ln16] = y;
                }
            }
        }
    }
}

// ---------------------------------------------------------------------------
extern "C" void kernel_launch(void* const* d_in, const int* in_sizes, int n_in,
                              void* d_out, int out_size, void* d_ws, size_t ws_size,
                              hipStream_t stream)
{
    const float* x_user = (const float*)d_in[0];
    const float* x_item = (const float*)d_in[1];
    const float* W_init = (const float*)d_in[2];
    const float* b_init = (const float*)d_in[3];
    const float* mlp_W  = (const float*)d_in[4];
    const float* mlp_b  = (const float*)d_in[5];
    const float* eps    = (const float*)d_in[6];
    const float* ln_g   = (const float*)d_in[7];
    const float* ln_b   = (const float*)d_in[8];
    const int* edge_ui  = (const int*)d_in[9];
    const int* edge_iu  = (const int*)d_in[10];

    float* xu = (float*)d_out;                      // [N_USER,128]
    float* xi = xu + (size_t)N_USER * CDIM;         // [N_ITEM,128]

    float* tu = (float*)d_ws;                       // 51.2 MB
    float* ti = tu + (size_t)N_USER * CDIM;         // 25.6 MB
    int* off_all = (int*)(ti + (size_t)N_ITEM * CDIM);
    int* cursor  = off_all + (N_SEG + 4);
    int* bsum    = cursor + N_SEG;
    int* srcbuf  = bsum + (NB_SCAN + 2);            // 2*NEDGE

    const int gU = (N_USER + 127) / 128;            // 782
    const int gI = (N_ITEM + 127) / 128;            // 391
    const int gSeg = (N_SEG + 256) / 256;
    const int gE = (NEDGE + 255) / 256;             // 2344
    const int gGather = (N_ITEM + 3) / 4 + (N_USER + 3) / 4;

    // CSR prep
    zero_i32<<<(N_SEG + 255) / 256, 256, 0, stream>>>(off_all, N_SEG);
    hist_k<<<gE, 256, 0, stream>>>(edge_ui, edge_iu, off_all);
    block_scan<<<NB_SCAN, 256, 0, stream>>>(off_all, bsum, N_SEG);
    scan_bsums<<<1, 1024, 0, stream>>>(bsum);
    add_offsets<<<gSeg, 256, 0, stream>>>(off_all, bsum, cursor, N_SEG);
    fill_k<<<gE, 256, 0, stream>>>(edge_ui, edge_iu, cursor, srcbuf);

    // initial projection
    gemm128<false><<<gU, 256, 0, stream>>>(x_user, W_init,         b_init,       xu, N_USER);
    gemm128<false><<<gI, 256, 0, stream>>>(x_item, W_init + 16384, b_init + 128, xi, N_ITEM);

    for (int l = 0; l < 2; ++l) {
        gather_both<<<gGather, 256, 0, stream>>>(
            xu, xi, eps + 2 * l, off_all, srcbuf, ti, tu);
        mlp_ln_both<<<gI + gU, 256, 0, stream>>>(
            ti, tu, mlp_W + (size_t)l * 4 * 16384, mlp_b + l * 4 * 128,
            ln_g + l * 2 * 128, ln_b + l * 2 * 128, xi, xu);
    }
}

// Round 8
// 627.695 us; speedup vs baseline: 1.3576x; 1.1272x over previous
//
#include <hip/hip_runtime.h>
#include <cstdint>
#include <cstddef>

#define N_USER 100000
#define N_ITEM 50000
#define CDIM   128
#define NEDGE  600000
#define N_SEG  (N_ITEM + N_USER)          // item segments first, then user
#define NB_SCAN ((N_SEG + 255) / 256)     // 586 scan blocks

typedef __bf16 bf16_t;
typedef bf16_t bfvec8 __attribute__((ext_vector_type(8)));
typedef bf16_t bfvec4 __attribute__((ext_vector_type(4)));
typedef float  f32x4  __attribute__((ext_vector_type(4)));

// LDS row stride for 128-wide bf16 tiles: 136 elems = 272 B. 16B-aligned rows,
// fragment reads land 2 lanes/bank (free, m136). Proven R3..R7.
#define LDW 136

// Stage a 128x128 fp32 weight (row-major [k][n]) into LDS as bf16 Wt[n][k].
static __device__ inline void stage_w(bf16_t* Wt, const float* __restrict__ W, int tid) {
    const f32x4* W4 = reinterpret_cast<const f32x4*>(W);
    #pragma unroll
    for (int i = 0; i < 16; ++i) {
        int cidx = i * 256 + tid;
        int base = cidx * 4;
        int k  = base >> 7;
        int n0 = base & 127;
        f32x4 v = W4[cidx];
        #pragma unroll
        for (int j = 0; j < 4; ++j) Wt[(n0 + j) * LDW + k] = (bf16_t)v[j];
    }
}

// ---------------------------------------------------------------------------
// Init GEMM: Y[M,128] = X@W + bias, X fp32 (raw inputs), Y bf16 (ws).
// MFMA 16x16x32_bf16: A[m=lane&15][k=quad*8+j], B[k][n=lane&15],
// D reg r -> row=quad*4+r, col=lane&15  (proven layouts).
// ---------------------------------------------------------------------------
__global__ __launch_bounds__(256) void gemm_init(
    const float* __restrict__ X,
    const float* __restrict__ W,
    const float* __restrict__ B,
    bf16_t* __restrict__ Y, int M)
{
    __shared__ __align__(16) bf16_t Wt[128 * LDW];
    const int tid = threadIdx.x;
    stage_w(Wt, W, tid);
    __syncthreads();

    const int wave = tid >> 6, lane = tid & 63;
    const int quad = lane >> 4, ln16 = lane & 15;

    #pragma unroll
    for (int s = 0; s < 2; ++s) {
        int row0 = blockIdx.x * 128 + s * 64 + wave * 16;
        int arow = row0 + ln16;
        int arow_c = arow < M ? arow : 0;

        bfvec8 a[4];
        const float* xp = X + (size_t)arow_c * CDIM + quad * 8;
        #pragma unroll
        for (int kc = 0; kc < 4; ++kc) {
            f32x4 lo = *reinterpret_cast<const f32x4*>(xp + kc * 32);
            f32x4 hi = *reinterpret_cast<const f32x4*>(xp + kc * 32 + 4);
            #pragma unroll
            for (int j = 0; j < 4; ++j) {
                a[kc][j]     = (bf16_t)lo[j];
                a[kc][j + 4] = (bf16_t)hi[j];
            }
        }

        f32x4 acc[8];
        #pragma unroll
        for (int t = 0; t < 8; ++t) acc[t] = (f32x4){0.f, 0.f, 0.f, 0.f};
        #pragma unroll
        for (int t = 0; t < 8; ++t) {
            const bf16_t* wp = &Wt[(t * 16 + ln16) * LDW + quad * 8];
            #pragma unroll
            for (int kc = 0; kc < 4; ++kc) {
                bfvec8 b = *reinterpret_cast<const bfvec8*>(wp + kc * 32);
                acc[t] = __builtin_amdgcn_mfma_f32_16x16x32_bf16(a[kc], b, acc[t], 0, 0, 0);
            }
        }

        if (row0 < M) {
            #pragma unroll
            for (int t = 0; t < 8; ++t) {
                int col = t * 16 + ln16;
                float bias = B[col];
                #pragma unroll
                for (int r = 0; r < 4; ++r) {
                    int row = row0 + quad * 4 + r;
                    if (row < M) Y[(size_t)row * CDIM + col] = (bf16_t)(acc[t][r] + bias);
                }
            }
        }
    }
}

// ---------------------------------------------------------------------------
// CSR build pieces (proven)
// ---------------------------------------------------------------------------
__global__ __launch_bounds__(256) void zero_i32(int* __restrict__ p, int n)
{
    int i = blockIdx.x * 256 + threadIdx.x;
    if (i < n) p[i] = 0;
}

__global__ __launch_bounds__(256) void hist_k(
    const int* __restrict__ edge_ui, const int* __restrict__ edge_iu,
    int* __restrict__ deg)
{
    int i = blockIdx.x * 256 + threadIdx.x;
    if (i >= NEDGE) return;
    atomicAdd(&deg[edge_ui[NEDGE + i]], 1);
    atomicAdd(&deg[N_ITEM + edge_iu[NEDGE + i]], 1);
}

__global__ __launch_bounds__(256) void block_scan(
    int* __restrict__ off, int* __restrict__ bsum, int n)
{
    __shared__ int sh[256];
    int tid = threadIdx.x;
    int i = blockIdx.x * 256 + tid;
    int v = (i < n) ? off[i] : 0;
    sh[tid] = v;
    __syncthreads();
    #pragma unroll
    for (int d = 1; d < 256; d <<= 1) {
        int t = (tid >= d) ? sh[tid - d] : 0;
        __syncthreads();
        sh[tid] += t;
        __syncthreads();
    }
    if (i < n) off[i] = sh[tid] - v;
    if (tid == 255) bsum[blockIdx.x] = sh[255];
}

__global__ __launch_bounds__(1024) void scan_bsums(int* __restrict__ bsum)
{
    __shared__ int sh[1024];
    int tid = threadIdx.x;
    int v = (tid < NB_SCAN) ? bsum[tid] : 0;
    sh[tid] = v;
    __syncthreads();
    #pragma unroll
    for (int d = 1; d < 1024; d <<= 1) {
        int t = (tid >= d) ? sh[tid - d] : 0;
        __syncthreads();
        sh[tid] += t;
        __syncthreads();
    }
    if (tid < NB_SCAN) bsum[tid] = sh[tid] - v;
    if (tid == 1023) bsum[NB_SCAN] = sh[1023];
}

__global__ __launch_bounds__(256) void add_offsets(
    int* __restrict__ off, const int* __restrict__ bsum,
    int* __restrict__ cursor, int n)
{
    int i = blockIdx.x * 256 + threadIdx.x;
    if (i < n) {
        int o = off[i] + bsum[i >> 8];
        off[i] = o;
        cursor[i] = o;
    } else if (i == n) {
        off[n] = bsum[NB_SCAN];
    }
}

// standalone bucket fill — no LDS, high occupancy (R5 post-mortem)
__global__ __launch_bounds__(256) void fill_k(
    const int* __restrict__ edge_ui, const int* __restrict__ edge_iu,
    int* __restrict__ cursor, int* __restrict__ srcbuf)
{
    int i = blockIdx.x * 256 + threadIdx.x;
    if (i >= NEDGE) return;
    {
        int dst = edge_ui[NEDGE + i];
        int slot = atomicAdd(&cursor[dst], 1);
        srcbuf[slot] = edge_ui[i];
    }
    {
        int dst = edge_iu[NEDGE + i];
        int slot = atomicAdd(&cursor[N_ITEM + dst], 1);
        srcbuf[slot] = edge_iu[i];
    }
}

// ---------------------------------------------------------------------------
// Gather + GIN combine, bf16 features, fp32 accumulate. One wave per dst
// node; lane holds bfvec4 (8 B, 32 lanes/row = 256 B); half-waves alternate
// neighbors, combined via lane^32 shuffle. out = bf16((1+eps)*x + sum F).
// ---------------------------------------------------------------------------
__global__ __launch_bounds__(256) void gather_both(
    const bf16_t* __restrict__ xu, const bf16_t* __restrict__ xi,
    const float* __restrict__ eps2,            // eps + 2*l: [item, user]
    const int* __restrict__ off_all, const int* __restrict__ srcbuf,
    bf16_t* __restrict__ ti, bf16_t* __restrict__ tu)
{
    const int gBI = (N_ITEM + 3) / 4;
    int b = blockIdx.x;
    bool isItem = b < gBI;
    int wave = threadIdx.x >> 6;
    int node = (isItem ? b : b - gBI) * 4 + wave;
    int n = isItem ? N_ITEM : N_USER;
    if (node >= n) return;

    const bfvec4* F = reinterpret_cast<const bfvec4*>(isItem ? xu : xi);
    const bfvec4* X = reinterpret_cast<const bfvec4*>(isItem ? xi : xu);
    const int* off = isItem ? off_all : off_all + N_ITEM;
    bfvec4* out = reinterpret_cast<bfvec4*>(isItem ? ti : tu);
    float s = 1.f + (isItem ? eps2[0] : eps2[1]);

    int l32  = threadIdx.x & 31;
    int half = (threadIdx.x >> 5) & 1;
    int start = off[node], end = off[node + 1];

    f32x4 acc = (f32x4){0.f, 0.f, 0.f, 0.f};
    int e = start + half;
    for (; e + 6 < end; e += 8) {
        bfvec4 v0 = F[(size_t)srcbuf[e]     * 32 + l32];
        bfvec4 v1 = F[(size_t)srcbuf[e + 2] * 32 + l32];
        bfvec4 v2 = F[(size_t)srcbuf[e + 4] * 32 + l32];
        bfvec4 v3 = F[(size_t)srcbuf[e + 6] * 32 + l32];
        #pragma unroll
        for (int j = 0; j < 4; ++j)
            acc[j] += ((float)v0[j] + (float)v1[j]) + ((float)v2[j] + (float)v3[j]);
    }
    for (; e + 2 < end; e += 4) {
        bfvec4 v0 = F[(size_t)srcbuf[e]     * 32 + l32];
        bfvec4 v1 = F[(size_t)srcbuf[e + 2] * 32 + l32];
        #pragma unroll
        for (int j = 0; j < 4; ++j) acc[j] += (float)v0[j] + (float)v1[j];
    }
    for (; e < end; e += 2) {
        bfvec4 v = F[(size_t)srcbuf[e] * 32 + l32];
        #pragma unroll
        for (int j = 0; j < 4; ++j) acc[j] += (float)v[j];
    }
    #pragma unroll
    for (int j = 0; j < 4; ++j) acc[j] += __shfl_xor(acc[j], 32, 64);

    if (half == 0) {
        bfvec4 xv = X[(size_t)node * 32 + l32];
        bfvec4 o;
        #pragma unroll
        for (int j = 0; j < 4; ++j) o[j] = (bf16_t)(s * (float)xv[j] + acc[j]);
        out[(size_t)node * 32 + l32] = o;
    }
}

// ---------------------------------------------------------------------------
// Fused MLP (linear->ReLU x2) + LayerNorm + ReLU, both node types,
// 128 rows/block. A loaded directly as bf16 (no cvt). H1 round-trips
// through At (bf16, LDW stride). ReLU after BOTH linears (R6 fix), then LN.
// Output: bf16 to ws (l=0) or fp32 to d_out (l=1), runtime flag.
// LDS 69,632 B -> 2 blocks/CU.
// ---------------------------------------------------------------------------
__global__ __launch_bounds__(256) void mlp_ln_both(
    const bf16_t* __restrict__ ti, const bf16_t* __restrict__ tu,
    const float* __restrict__ mlpW,   // mlp_W + l*4*16384
    const float* __restrict__ mlpb,   // mlp_b + l*4*128
    const float* __restrict__ lng,    // ln_g + l*2*128
    const float* __restrict__ lnb,    // ln_b + l*2*128
    bf16_t* __restrict__ xib, bf16_t* __restrict__ xub,   // bf16 outs (l=0)
    float* __restrict__ xif, float* __restrict__ xuf,     // fp32 outs (l=1)
    int f32out)
{
    __shared__ __align__(16) bf16_t Wt[128 * LDW];
    __shared__ __align__(16) bf16_t At[128 * LDW];

    const int gBI = (N_ITEM + 127) / 128;
    int b = blockIdx.x;
    bool isItem = b < gBI;
    const bf16_t* X = isItem ? ti : tu;
    bf16_t* Yb      = isItem ? xib : xub;
    float*  Yf      = isItem ? xif : xuf;
    int M  = isItem ? N_ITEM : N_USER;
    int bx = isItem ? b : b - gBI;
    // edge type 0 = (user->item) => item dst; 1 = (item->user) => user dst
    const float* W1 = mlpW + (isItem ? 0 : 2) * 16384;
    const float* W2 = W1 + 16384;
    const float* B1 = mlpb + (isItem ? 0 : 2) * 128;
    const float* B2 = B1 + 128;
    // node type 0 = user, 1 = item
    const float* G  = lng + (isItem ? 128 : 0);
    const float* Bb = lnb + (isItem ? 128 : 0);

    const int tid = threadIdx.x;
    stage_w(Wt, W1, tid);
    __syncthreads();

    const int wave = tid >> 6, lane = tid & 63;
    const int quad = lane >> 4, ln16 = lane & 15;
    const int rowBase = bx * 128;

    // ---- GEMM1: X -> relu(X@W1+b1) -> At[row][k] ----
    #pragma unroll
    for (int s = 0; s < 2; ++s) {
        int row0l = s * 64 + wave * 16;
        int arow = rowBase + row0l + ln16;
        int arow_c = arow < M ? arow : 0;

        bfvec8 a[4];
        const bf16_t* xp = X + (size_t)arow_c * CDIM + quad * 8;
        #pragma unroll
        for (int kc = 0; kc < 4; ++kc)
            a[kc] = *reinterpret_cast<const bfvec8*>(xp + kc * 32);

        f32x4 acc[8];
        #pragma unroll
        for (int t = 0; t < 8; ++t) acc[t] = (f32x4){0.f, 0.f, 0.f, 0.f};
        #pragma unroll
        for (int t = 0; t < 8; ++t) {
            const bf16_t* wp = &Wt[(t * 16 + ln16) * LDW + quad * 8];
            #pragma unroll
            for (int kc = 0; kc < 4; ++kc) {
                bfvec8 bv = *reinterpret_cast<const bfvec8*>(wp + kc * 32);
                acc[t] = __builtin_amdgcn_mfma_f32_16x16x32_bf16(a[kc], bv, acc[t], 0, 0, 0);
            }
        }

        #pragma unroll
        for (int t = 0; t < 8; ++t) {
            int col = t * 16 + ln16;
            float bias = B1[col];
            #pragma unroll
            for (int r = 0; r < 4; ++r) {
                float v = acc[t][r] + bias;
                v = v > 0.f ? v : 0.f;
                At[(row0l + quad * 4 + r) * LDW + col] = (bf16_t)v;
            }
        }
    }
    __syncthreads();
    stage_w(Wt, W2, tid);      // overwrite W1; all GEMM1 reads complete
    __syncthreads();

    // ---- GEMM2 from At + bias + ReLU + LayerNorm + ReLU -> Y ----
    #pragma unroll
    for (int s = 0; s < 2; ++s) {
        int row0l = s * 64 + wave * 16;
        int ml = row0l + ln16;

        bfvec8 a[4];
        #pragma unroll
        for (int kc = 0; kc < 4; ++kc)
            a[kc] = *reinterpret_cast<const bfvec8*>(&At[ml * LDW + kc * 32 + quad * 8]);

        f32x4 acc[8];
        #pragma unroll
        for (int t = 0; t < 8; ++t) acc[t] = (f32x4){0.f, 0.f, 0.f, 0.f};
        #pragma unroll
        for (int t = 0; t < 8; ++t) {
            const bf16_t* wp = &Wt[(t * 16 + ln16) * LDW + quad * 8];
            #pragma unroll
            for (int kc = 0; kc < 4; ++kc) {
                bfvec8 bv = *reinterpret_cast<const bfvec8*>(wp + kc * 32);
                acc[t] = __builtin_amdgcn_mfma_f32_16x16x32_bf16(a[kc], bv, acc[t], 0, 0, 0);
            }
        }

        float gA[8], bA[8];
        #pragma unroll
        for (int t = 0; t < 8; ++t) {
            int col = t * 16 + ln16;
            float b2 = B2[col];
            #pragma unroll
            for (int r = 0; r < 4; ++r) {
                float v = acc[t][r] + b2;
                acc[t][r] = v > 0.f ? v : 0.f;       // ReLU after 2nd linear (R6 fix)
            }
            gA[t] = G[col]; bA[t] = Bb[col];
        }

        // LN: row (quad*4+r) spans 8 regs x the 16 lanes of this quad
        #pragma unroll
        for (int r = 0; r < 4; ++r) {
            float sm = 0.f;
            #pragma unroll
            for (int t = 0; t < 8; ++t) sm += acc[t][r];
            #pragma unroll
            for (int m = 8; m >= 1; m >>= 1) sm += __shfl_xor(sm, m, 16);
            float mean = sm * (1.f / 128.f);
            float sq = 0.f;
            #pragma unroll
            for (int t = 0; t < 8; ++t) { float d = acc[t][r] - mean; sq += d * d; }
            #pragma unroll
            for (int m = 8; m >= 1; m >>= 1) sq += __shfl_xor(sq, m, 16);
            float rs = rsqrtf(sq * (1.f / 128.f) + 1e-5f);

            int row = rowBase + row0l + quad * 4 + r;
            if (row < M) {
                if (f32out) {
                    #pragma unroll
                    for (int t = 0; t < 8; ++t) {
                        float y = (acc[t][r] - mean) * rs * gA[t] + bA[t];
                        y = y > 0.f ? y : 0.f;
                        Yf[(size_t)row * CDIM + t * 16 + ln16] = y;
                    }
                } else {
                    #pragma unroll
                    for (int t = 0; t < 8; ++t) {
                        float y = (acc[t][r] - mean) * rs * gA[t] + bA[t];
                        y = y > 0.f ? y : 0.f;
                        Yb[(size_t)row * CDIM + t * 16 + ln16] = (bf16_t)y;
                    }
                }
            }
        }
    }
}

// ---------------------------------------------------------------------------
extern "C" void kernel_launch(void* const* d_in, const int* in_sizes, int n_in,
                              void* d_out, int out_size, void* d_ws, size_t ws_size,
                              hipStream_t stream)
{
    const float* x_user = (const float*)d_in[0];
    const float* x_item = (const float*)d_in[1];
    const float* W_init = (const float*)d_in[2];
    const float* b_init = (const float*)d_in[3];
    const float* mlp_W  = (const float*)d_in[4];
    const float* mlp_b  = (const float*)d_in[5];
    const float* eps    = (const float*)d_in[6];
    const float* ln_g   = (const float*)d_in[7];
    const float* ln_b   = (const float*)d_in[8];
    const int* edge_ui  = (const int*)d_in[9];
    const int* edge_iu  = (const int*)d_in[10];

    // final fp32 outputs
    float* xuf = (float*)d_out;                     // [N_USER,128]
    float* xif = xuf + (size_t)N_USER * CDIM;       // [N_ITEM,128]

    // ws: bf16 activations + CSR
    char* w = (char*)d_ws;
    bf16_t* xub = (bf16_t*)w;                                  // 25.6 MB
    bf16_t* xib = xub + (size_t)N_USER * CDIM;                 // 12.8 MB
    bf16_t* tub = xib + (size_t)N_ITEM * CDIM;                 // 25.6 MB
    bf16_t* tib = tub + (size_t)N_USER * CDIM;                 // 12.8 MB
    int* off_all = (int*)(tib + (size_t)N_ITEM * CDIM);        // N_SEG+1
    int* cursor  = off_all + (N_SEG + 4);
    int* bsum    = cursor + N_SEG;
    int* srcbuf  = bsum + (NB_SCAN + 2);                       // 2*NEDGE

    const int gU = (N_USER + 127) / 128;            // 782
    const int gI = (N_ITEM + 127) / 128;            // 391
    const int gSeg = (N_SEG + 256) / 256;
    const int gE = (NEDGE + 255) / 256;             // 2344
    const int gGather = (N_ITEM + 3) / 4 + (N_USER + 3) / 4;

    // CSR prep
    zero_i32<<<(N_SEG + 255) / 256, 256, 0, stream>>>(off_all, N_SEG);
    hist_k<<<gE, 256, 0, stream>>>(edge_ui, edge_iu, off_all);
    block_scan<<<NB_SCAN, 256, 0, stream>>>(off_all, bsum, N_SEG);
    scan_bsums<<<1, 1024, 0, stream>>>(bsum);
    add_offsets<<<gSeg, 256, 0, stream>>>(off_all, bsum, cursor, N_SEG);
    fill_k<<<gE, 256, 0, stream>>>(edge_ui, edge_iu, cursor, srcbuf);

    // initial projection -> bf16 ws
    gemm_init<<<gU, 256, 0, stream>>>(x_user, W_init,         b_init,       xub, N_USER);
    gemm_init<<<gI, 256, 0, stream>>>(x_item, W_init + 16384, b_init + 128, xib, N_ITEM);

    for (int l = 0; l < 2; ++l) {
        gather_both<<<gGather, 256, 0, stream>>>(
            xub, xib, eps + 2 * l, off_all, srcbuf, tib, tub);
        mlp_ln_both<<<gI + gU, 256, 0, stream>>>(
            tib, tub, mlp_W + (size_t)l * 4 * 16384, mlp_b + l * 4 * 128,
            ln_g + l * 2 * 128, ln_b + l * 2 * 128,
            xib, xub, xif, xuf, (l == 1) ? 1 : 0);
    }
}